// Round 1
// baseline (459.843 us; speedup 1.0000x reference)
//
#include <hip/hip_runtime.h>
#include <hip/hip_bf16.h>

#define DEVI __device__ __forceinline__

typedef __hip_bfloat16 bf16;
typedef __attribute__((ext_vector_type(8))) short bf16x8;   // 8 bf16 = 4 VGPRs (MFMA A/B frag)
typedef __attribute__((ext_vector_type(4))) float f32x4;    // MFMA C/D frag

constexpr int S  = 2048;
constexpr int B  = 2;
constexpr int D  = 1024;
constexpr int H  = 16;
constexpr int DH = 64;
constexpr int M  = S * B;   // 4096 rows for projection GEMMs
constexpr int K  = D;       // 1024 reduction dim

DEVI f32x4 mfma16(bf16x8 a, bf16x8 b, f32x4 c) {
  return __builtin_amdgcn_mfma_f32_16x16x32_bf16(a, b, c, 0, 0, 0);
}

DEVI void cvt8_store(bf16* dst, float4 a, float4 b) {
  alignas(16) bf16 t[8];
  t[0] = __float2bfloat16(a.x); t[1] = __float2bfloat16(a.y);
  t[2] = __float2bfloat16(a.z); t[3] = __float2bfloat16(a.w);
  t[4] = __float2bfloat16(b.x); t[5] = __float2bfloat16(b.y);
  t[6] = __float2bfloat16(b.z); t[7] = __float2bfloat16(b.w);
  *(bf16x8*)dst = *(const bf16x8*)t;
}

// ---------------- mask -> bitfield (one u64 per 64 cols) ----------------
__global__ __launch_bounds__(256) void maskbits_k(const int* __restrict__ mask,
                                                  unsigned long long* __restrict__ bits) {
  int idx = blockIdx.x * 256 + threadIdx.x;           // row-major over [2048][2048]
  int m = mask[idx];
  unsigned long long b = __ballot(m != 0);            // wave64: 64 consecutive cols
  if ((threadIdx.x & 63) == 0) bits[idx >> 6] = b;
}

// ---------------- projection GEMM: C[m,n] = sum_d A[m,d]*W[n,d] + bias[n] ----------------
// MODE 0: scatter bf16 to [H,B,S,Dh] (Q,K)   MODE 1: scatter bf16 to [H,B,Dh,S] (V^T)
// MODE 2: f32 row-major [M,D] (final output)
template<int MODE>
__global__ __launch_bounds__(256)
void gemm_proj(const float* __restrict__ A, const float* __restrict__ W,
               const float* __restrict__ bias, bf16* __restrict__ obf,
               float* __restrict__ of32) {
  __shared__ bf16 lA[128 * 40];   // [128 rows][32 k + 8 pad] -> 2-way banks (free)
  __shared__ bf16 lB[128 * 40];

  const int tid  = threadIdx.x;
  const int lane = tid & 63;
  const int wave = tid >> 6;
  const int m0   = blockIdx.x * 128;
  const int n0   = blockIdx.y * 128;
  const int wm   = (wave >> 1) * 64;   // wave's 64x64 sub-tile
  const int wn   = (wave & 1) * 64;
  const int lr   = lane & 15;
  const int lg   = lane >> 4;

  f32x4 acc[4][4] = {};

  const int srow = tid >> 2;           // staging: 256 thr cover 64 rows x 32 cols per pass
  const int sc8  = (tid & 3) * 8;

  for (int k0 = 0; k0 < K; k0 += 32) {
    __syncthreads();
    #pragma unroll
    for (int i = 0; i < 2; ++i) {
      int row = srow + i * 64;
      const float* ga = A + (size_t)(m0 + row) * K + k0 + sc8;
      const float* gb = W + (size_t)(n0 + row) * K + k0 + sc8;
      float4 a0 = *(const float4*)ga;
      float4 a1 = *(const float4*)(ga + 4);
      float4 b0 = *(const float4*)gb;
      float4 b1 = *(const float4*)(gb + 4);
      cvt8_store(&lA[row * 40 + sc8], a0, a1);
      cvt8_store(&lB[row * 40 + sc8], b0, b1);
    }
    __syncthreads();

    bf16x8 af[4], bfv[4];
    #pragma unroll
    for (int f = 0; f < 4; ++f) {
      af[f]  = *(const bf16x8*)&lA[(wm + f * 16 + lr) * 40 + lg * 8];
      bfv[f] = *(const bf16x8*)&lB[(wn + f * 16 + lr) * 40 + lg * 8];
    }
    #pragma unroll
    for (int i = 0; i < 4; ++i)
      #pragma unroll
      for (int j = 0; j < 4; ++j)
        acc[i][j] = mfma16(af[i], bfv[j], acc[i][j]);
  }

  // epilogue: C frag mapping col = lane&15, row = (lane>>4)*4 + r  [m89-verified]
  #pragma unroll
  for (int j = 0; j < 4; ++j) {
    int gcol = n0 + wn + j * 16 + lr;
    float bv = bias[gcol];
    #pragma unroll
    for (int i = 0; i < 4; ++i) {
      #pragma unroll
      for (int r = 0; r < 4; ++r) {
        int grow = m0 + wm + i * 16 + lg * 4 + r;
        float v = acc[i][j][r] + bv;
        if (MODE == 2) {
          of32[(size_t)grow * D + gcol] = v;
        } else {
          int s  = grow >> 1, b = grow & 1;        // m = s*B + b  (B=2)
          int h  = gcol >> 6, dh = gcol & 63;
          size_t idx = (MODE == 0)
              ? (((size_t)(h * 2 + b) * S + s) * 64 + dh)     // [H,B,S,Dh]
              : (((size_t)(h * 2 + b) * 64 + dh) * S + s);    // [H,B,Dh,S]
          obf[idx] = __float2bfloat16(v);
        }
      }
    }
  }
}

// ---------------- fused attention: scores -> softmax -> write weights -> PV ----------------
__global__ __launch_bounds__(256)
void attn_k(const bf16* __restrict__ qh, const bf16* __restrict__ kh,
            const bf16* __restrict__ vt, const unsigned long long* __restrict__ mbits,
            float* __restrict__ wout, float* __restrict__ ao) {
  __shared__ bf16 lK[64 * 72];        // [64 sk][64 dh + 8 pad]
  __shared__ bf16 lV[64 * 72];        // [64 dh][64 sk + 8 pad]
  __shared__ bf16 lW[4][32 * 40];     // per-wave P tile: [32 q][32 sk + 8 pad]

  const int tid = threadIdx.x, lane = tid & 63, wave = tid >> 6;
  const int hb = blockIdx.y;                       // h*2 + b
  const int q0 = blockIdx.x * 128 + wave * 32;     // this wave's 32 q rows
  const bf16* Kb = kh + (size_t)hb * S * DH;
  const bf16* Vb = vt + (size_t)hb * DH * S;
  const bf16* Qb = qh + (size_t)hb * S * DH;
  const int lr = lane & 15, lg = lane >> 4;
  const float scale = 0.125f;                       // 1/sqrt(64)

  // Q fragments in registers: 2 m-frags x 2 k-chunks (Dh=64)
  bf16x8 qf[2][2];
  #pragma unroll
  for (int mf = 0; mf < 2; ++mf)
    #pragma unroll
    for (int kk = 0; kk < 2; ++kk)
      qf[mf][kk] = *(const bf16x8*)&Qb[(size_t)(q0 + mf * 16 + lr) * DH + kk * 32 + lg * 8];

  float mrow[2][4], lrow[2][4];
  #pragma unroll
  for (int mf = 0; mf < 2; ++mf)
    #pragma unroll
    for (int j = 0; j < 4; ++j) { mrow[mf][j] = -3.0e38f; lrow[mf][j] = 0.f; }

  const int srow = tid >> 3;           // staging: chunk = tid + i*256 -> row=c/8, col8=(c%8)*8
  const int sc8  = (tid & 7) * 8;

  #define STAGE_K(t) { \
    _Pragma("unroll") for (int i = 0; i < 2; ++i) { \
      int row = srow + i * 32; \
      float4 v = *(const float4*)&Kb[(size_t)((t) * 64 + row) * DH + sc8]; \
      *(float4*)&lK[row * 72 + sc8] = v; } }
  #define STAGE_V(t) { \
    _Pragma("unroll") for (int i = 0; i < 2; ++i) { \
      int row = srow + i * 32; \
      float4 v = *(const float4*)&Vb[(size_t)row * S + (t) * 64 + sc8]; \
      *(float4*)&lV[row * 72 + sc8] = v; } }

  // ---- pass A: row max (no cross-lane work inside loop) ----
  for (int t = 0; t < 32; ++t) {
    __syncthreads();
    STAGE_K(t);
    __syncthreads();
    #pragma unroll
    for (int mf = 0; mf < 2; ++mf) {
      unsigned long long mw[4];
      #pragma unroll
      for (int j = 0; j < 4; ++j)
        mw[j] = mbits[(size_t)(q0 + mf * 16 + lg * 4 + j) * 32 + t];
      #pragma unroll
      for (int c = 0; c < 4; ++c) {
        f32x4 sa = {0.f, 0.f, 0.f, 0.f};
        bf16x8 k0v = *(const bf16x8*)&lK[(c * 16 + lr) * 72 + lg * 8];
        bf16x8 k1v = *(const bf16x8*)&lK[(c * 16 + lr) * 72 + 32 + lg * 8];
        sa = mfma16(qf[mf][0], k0v, sa);
        sa = mfma16(qf[mf][1], k1v, sa);
        int cb = c * 16 + lr;
        #pragma unroll
        for (int j = 0; j < 4; ++j) {
          float sv = ((mw[j] >> cb) & 1ull) ? sa[j] * scale : -1e9f;
          mrow[mf][j] = fmaxf(mrow[mf][j], sv);
        }
      }
    }
  }
  #pragma unroll
  for (int mf = 0; mf < 2; ++mf)
    #pragma unroll
    for (int j = 0; j < 4; ++j) {
      float v = mrow[mf][j];
      #pragma unroll
      for (int off = 1; off < 16; off <<= 1) v = fmaxf(v, __shfl_xor(v, off, 16));
      mrow[mf][j] = v;
    }

  // ---- pass B: row sum of exp(s - max) ----
  for (int t = 0; t < 32; ++t) {
    __syncthreads();
    STAGE_K(t);
    __syncthreads();
    #pragma unroll
    for (int mf = 0; mf < 2; ++mf) {
      unsigned long long mw[4];
      #pragma unroll
      for (int j = 0; j < 4; ++j)
        mw[j] = mbits[(size_t)(q0 + mf * 16 + lg * 4 + j) * 32 + t];
      #pragma unroll
      for (int c = 0; c < 4; ++c) {
        f32x4 sa = {0.f, 0.f, 0.f, 0.f};
        bf16x8 k0v = *(const bf16x8*)&lK[(c * 16 + lr) * 72 + lg * 8];
        bf16x8 k1v = *(const bf16x8*)&lK[(c * 16 + lr) * 72 + 32 + lg * 8];
        sa = mfma16(qf[mf][0], k0v, sa);
        sa = mfma16(qf[mf][1], k1v, sa);
        int cb = c * 16 + lr;
        #pragma unroll
        for (int j = 0; j < 4; ++j) {
          float sv = ((mw[j] >> cb) & 1ull) ? sa[j] * scale : -1e9f;
          lrow[mf][j] += __expf(sv - mrow[mf][j]);
        }
      }
    }
  }
  #pragma unroll
  for (int mf = 0; mf < 2; ++mf)
    #pragma unroll
    for (int j = 0; j < 4; ++j) {
      float v = lrow[mf][j];
      #pragma unroll
      for (int off = 1; off < 16; off <<= 1) v += __shfl_xor(v, off, 16);
      lrow[mf][j] = 1.0f / v;   // now holds 1/sum
    }

  // ---- pass C: w = exp(s-m)/l -> write to d_out, bf16 -> LDS -> PV MFMA ----
  f32x4 oacc[2][4] = {};
  for (int t = 0; t < 32; ++t) {
    __syncthreads();
    STAGE_K(t);
    STAGE_V(t);
    __syncthreads();
    unsigned long long mw[2][4];
    #pragma unroll
    for (int mf = 0; mf < 2; ++mf)
      #pragma unroll
      for (int j = 0; j < 4; ++j)
        mw[mf][j] = mbits[(size_t)(q0 + mf * 16 + lg * 4 + j) * 32 + t];

    #pragma unroll
    for (int u = 0; u < 2; ++u) {          // two 32-sk chunks per tile
      #pragma unroll
      for (int mf = 0; mf < 2; ++mf) {
        #pragma unroll
        for (int cc = 0; cc < 2; ++cc) {
          int c = u * 2 + cc;
          f32x4 sa = {0.f, 0.f, 0.f, 0.f};
          bf16x8 k0v = *(const bf16x8*)&lK[(c * 16 + lr) * 72 + lg * 8];
          bf16x8 k1v = *(const bf16x8*)&lK[(c * 16 + lr) * 72 + 32 + lg * 8];
          sa = mfma16(qf[mf][0], k0v, sa);
          sa = mfma16(qf[mf][1], k1v, sa);
          int cb = c * 16 + lr;
          #pragma unroll
          for (int j = 0; j < 4; ++j) {
            float sv = ((mw[mf][j] >> cb) & 1ull) ? sa[j] * scale : -1e9f;
            float w = __expf(sv - mrow[mf][j]) * lrow[mf][j];
            int row = mf * 16 + lg * 4 + j;
            wout[(size_t)(hb * S + q0 + row) * S + t * 64 + cb] = w;
            lW[wave][row * 40 + cc * 16 + lr] = __float2bfloat16(w);
          }
        }
      }
      // PV for this 32-sk chunk (per-wave LDS, same-wave deps -> no barrier)
      #pragma unroll
      for (int mf = 0; mf < 2; ++mf) {
        bf16x8 pa = *(const bf16x8*)&lW[wave][(mf * 16 + lr) * 40 + lg * 8];
        #pragma unroll
        for (int nf = 0; nf < 4; ++nf) {
          bf16x8 vb = *(const bf16x8*)&lV[(nf * 16 + lr) * 72 + u * 32 + lg * 8];
          oacc[mf][nf] = mfma16(pa, vb, oacc[mf][nf]);
        }
      }
    }
  }

  // epilogue: attn output -> ws as f32 [m = s*2+b][d = h*64+dh]
  int h = hb >> 1, b = hb & 1;
  #pragma unroll
  for (int mf = 0; mf < 2; ++mf)
    #pragma unroll
    for (int nf = 0; nf < 4; ++nf)
      #pragma unroll
      for (int r = 0; r < 4; ++r) {
        int sq = q0 + mf * 16 + lg * 4 + r;
        int d  = h * 64 + nf * 16 + lr;
        ao[(size_t)(sq * 2 + b) * D + d] = oacc[mf][nf][r];
      }
}

// ---------------- host ----------------
extern "C" void kernel_launch(void* const* d_in, const int* in_sizes, int n_in,
                              void* d_out, int out_size, void* d_ws, size_t ws_size,
                              hipStream_t stream) {
  const float* q    = (const float*)d_in[0];
  const float* k    = (const float*)d_in[1];
  const float* v    = (const float*)d_in[2];
  const int*   mask = (const int*)d_in[3];
  const float* Wq   = (const float*)d_in[4];
  const float* bq   = (const float*)d_in[5];
  const float* Wk   = (const float*)d_in[6];
  const float* bk   = (const float*)d_in[7];
  const float* Wv   = (const float*)d_in[8];
  const float* bv   = (const float*)d_in[9];
  const float* Wo   = (const float*)d_in[10];
  const float* bo   = (const float*)d_in[11];

  char* ws = (char*)d_ws;
  bf16* qh = (bf16*)(ws);                              // 8 MB  [H,B,S,Dh]
  bf16* kh = (bf16*)(ws + ((size_t)8  << 20));         // 8 MB  [H,B,S,Dh]
  bf16* vt = (bf16*)(ws + ((size_t)16 << 20));         // 8 MB  [H,B,Dh,S]
  float* ao = (float*)(ws + ((size_t)24 << 20));       // 16 MB [M,D]
  unsigned long long* mbits =
      (unsigned long long*)(ws + ((size_t)40 << 20));  // 512 KB

  float* outp = (float*)d_out;
  float* wout = outp + (size_t)M * D;                  // weights at +4194304

  maskbits_k<<<dim3((S * S) / 256), 256, 0, stream>>>(mask, mbits);

  dim3 gg(M / 128, D / 128);   // 32 x 8
  gemm_proj<0><<<gg, 256, 0, stream>>>(q, Wq, bq, qh, nullptr);
  gemm_proj<0><<<gg, 256, 0, stream>>>(k, Wk, bk, kh, nullptr);
  gemm_proj<1><<<gg, 256, 0, stream>>>(v, Wv, bv, vt, nullptr);

  dim3 ga(S / 128, H * B);     // 16 x 32
  attn_k<<<ga, 256, 0, stream>>>(qh, kh, vt, mbits, wout, ao);

  gemm_proj<2><<<gg, 256, 0, stream>>>(ao, Wo, bo, nullptr, outp);
}

// Round 2
// 444.783 us; speedup vs baseline: 1.0339x; 1.0339x over previous
//
#include <hip/hip_runtime.h>
#include <hip/hip_bf16.h>

#define DEVI __device__ __forceinline__

typedef __hip_bfloat16 bf16;
typedef __attribute__((ext_vector_type(8))) short bf16x8;   // 8 bf16 = 4 VGPRs (MFMA A/B frag)
typedef __attribute__((ext_vector_type(4))) float f32x4;    // MFMA C/D frag

constexpr int S  = 2048;
constexpr int B  = 2;
constexpr int D  = 1024;
constexpr int H  = 16;
constexpr int DH = 64;
constexpr int M  = S * B;   // 4096 rows for projection GEMMs
constexpr int K  = D;       // 1024 reduction dim

DEVI f32x4 mfma16(bf16x8 a, bf16x8 b, f32x4 c) {
  return __builtin_amdgcn_mfma_f32_16x16x32_bf16(a, b, c, 0, 0, 0);
}

DEVI void cvt8_store(bf16* dst, float4 a, float4 b) {
  alignas(16) bf16 t[8];
  t[0] = __float2bfloat16(a.x); t[1] = __float2bfloat16(a.y);
  t[2] = __float2bfloat16(a.z); t[3] = __float2bfloat16(a.w);
  t[4] = __float2bfloat16(b.x); t[5] = __float2bfloat16(b.y);
  t[6] = __float2bfloat16(b.z); t[7] = __float2bfloat16(b.w);
  *(bf16x8*)dst = *(const bf16x8*)t;
}

// ---------------- mask -> bitfield (one u64 per 64 cols) ----------------
__global__ __launch_bounds__(256) void maskbits_k(const int* __restrict__ mask,
                                                  unsigned long long* __restrict__ bits) {
  int idx = blockIdx.x * 256 + threadIdx.x;           // row-major over [2048][2048]
  int m = mask[idx];
  unsigned long long b = __ballot(m != 0);            // wave64: 64 consecutive cols
  if ((threadIdx.x & 63) == 0) bits[idx >> 6] = b;
}

// ---------------- fused Q/K/V projection GEMM (blockIdx.z selects tensor) ----------------
// z=0: Q -> [H,B,S,Dh] bf16    z=1: K -> [H,B,S,Dh] bf16    z=2: V -> [H,B,Dh,S] bf16
__global__ __launch_bounds__(256)
void gemm_qkv(const float* __restrict__ qp, const float* __restrict__ kp,
              const float* __restrict__ vp,
              const float* __restrict__ Wqp, const float* __restrict__ Wkp,
              const float* __restrict__ Wvp,
              const float* __restrict__ bqp, const float* __restrict__ bkp,
              const float* __restrict__ bvp,
              bf16* __restrict__ qh, bf16* __restrict__ kh, bf16* __restrict__ vt) {
  __shared__ bf16 lA[128 * 40];   // [128 rows][32 k + 8 pad]
  __shared__ bf16 lB[128 * 40];

  const int z = blockIdx.z;
  const float* A    = (z == 0) ? qp  : (z == 1) ? kp  : vp;
  const float* W    = (z == 0) ? Wqp : (z == 1) ? Wkp : Wvp;
  const float* bias = (z == 0) ? bqp : (z == 1) ? bkp : bvp;
  bf16* obf         = (z == 0) ? qh  : (z == 1) ? kh  : vt;
  const bool vmode  = (z == 2);

  const int tid  = threadIdx.x;
  const int lane = tid & 63;
  const int wave = tid >> 6;
  const int m0   = blockIdx.x * 128;
  const int n0   = blockIdx.y * 128;
  const int wm   = (wave >> 1) * 64;
  const int wn   = (wave & 1) * 64;
  const int lr   = lane & 15;
  const int lg   = lane >> 4;

  f32x4 acc[4][4] = {};

  const int srow = tid >> 2;
  const int sc8  = (tid & 3) * 8;

  for (int k0 = 0; k0 < K; k0 += 32) {
    __syncthreads();
    #pragma unroll
    for (int i = 0; i < 2; ++i) {
      int row = srow + i * 64;
      const float* ga = A + (size_t)(m0 + row) * K + k0 + sc8;
      const float* gb = W + (size_t)(n0 + row) * K + k0 + sc8;
      float4 a0 = *(const float4*)ga;
      float4 a1 = *(const float4*)(ga + 4);
      float4 b0 = *(const float4*)gb;
      float4 b1 = *(const float4*)(gb + 4);
      cvt8_store(&lA[row * 40 + sc8], a0, a1);
      cvt8_store(&lB[row * 40 + sc8], b0, b1);
    }
    __syncthreads();

    bf16x8 af[4], bfv[4];
    #pragma unroll
    for (int f = 0; f < 4; ++f) {
      af[f]  = *(const bf16x8*)&lA[(wm + f * 16 + lr) * 40 + lg * 8];
      bfv[f] = *(const bf16x8*)&lB[(wn + f * 16 + lr) * 40 + lg * 8];
    }
    #pragma unroll
    for (int i = 0; i < 4; ++i)
      #pragma unroll
      for (int j = 0; j < 4; ++j)
        acc[i][j] = mfma16(af[i], bfv[j], acc[i][j]);
  }

  #pragma unroll
  for (int j = 0; j < 4; ++j) {
    int gcol = n0 + wn + j * 16 + lr;
    float bv = bias[gcol];
    int h = gcol >> 6, dh = gcol & 63;
    #pragma unroll
    for (int i = 0; i < 4; ++i) {
      #pragma unroll
      for (int r = 0; r < 4; ++r) {
        int grow = m0 + wm + i * 16 + lg * 4 + r;
        float v = acc[i][j][r] + bv;
        int s = grow >> 1, b = grow & 1;             // m = s*B + b (B=2)
        size_t idx = vmode
            ? (((size_t)(h * 2 + b) * 64 + dh) * S + s)     // [H,B,Dh,S]
            : (((size_t)(h * 2 + b) * S + s) * 64 + dh);    // [H,B,S,Dh]
        obf[idx] = __float2bfloat16(v);
      }
    }
  }
}

// ---------------- output projection GEMM: f32 [M,D] ----------------
__global__ __launch_bounds__(256)
void gemm_out(const float* __restrict__ A, const float* __restrict__ W,
              const float* __restrict__ bias, float* __restrict__ of32) {
  __shared__ bf16 lA[128 * 40];
  __shared__ bf16 lB[128 * 40];

  const int tid  = threadIdx.x;
  const int lane = tid & 63;
  const int wave = tid >> 6;
  const int m0   = blockIdx.x * 128;
  const int n0   = blockIdx.y * 128;
  const int wm   = (wave >> 1) * 64;
  const int wn   = (wave & 1) * 64;
  const int lr   = lane & 15;
  const int lg   = lane >> 4;

  f32x4 acc[4][4] = {};
  const int srow = tid >> 2;
  const int sc8  = (tid & 3) * 8;

  for (int k0 = 0; k0 < K; k0 += 32) {
    __syncthreads();
    #pragma unroll
    for (int i = 0; i < 2; ++i) {
      int row = srow + i * 64;
      const float* ga = A + (size_t)(m0 + row) * K + k0 + sc8;
      const float* gb = W + (size_t)(n0 + row) * K + k0 + sc8;
      float4 a0 = *(const float4*)ga;
      float4 a1 = *(const float4*)(ga + 4);
      float4 b0 = *(const float4*)gb;
      float4 b1 = *(const float4*)(gb + 4);
      cvt8_store(&lA[row * 40 + sc8], a0, a1);
      cvt8_store(&lB[row * 40 + sc8], b0, b1);
    }
    __syncthreads();

    bf16x8 af[4], bfv[4];
    #pragma unroll
    for (int f = 0; f < 4; ++f) {
      af[f]  = *(const bf16x8*)&lA[(wm + f * 16 + lr) * 40 + lg * 8];
      bfv[f] = *(const bf16x8*)&lB[(wn + f * 16 + lr) * 40 + lg * 8];
    }
    #pragma unroll
    for (int i = 0; i < 4; ++i)
      #pragma unroll
      for (int j = 0; j < 4; ++j)
        acc[i][j] = mfma16(af[i], bfv[j], acc[i][j]);
  }

  #pragma unroll
  for (int j = 0; j < 4; ++j) {
    int gcol = n0 + wn + j * 16 + lr;
    float bv = bias[gcol];
    #pragma unroll
    for (int i = 0; i < 4; ++i)
      #pragma unroll
      for (int r = 0; r < 4; ++r) {
        int grow = m0 + wm + i * 16 + lg * 4 + r;
        of32[(size_t)grow * D + gcol] = acc[i][j][r] + bv;
      }
  }
}

// ---------------- fused attention: barrier-free, 2-pass online softmax ----------------
// Pass 1: QK^T (K frags from global/L2) -> running (m,l) online.  shfl-combine.
// Pass 2: QK^T again -> w = exp(s-m)/l -> store f32 weights, bf16->LDS repack -> PV.
__global__ __launch_bounds__(256)
void attn_k(const bf16* __restrict__ qh, const bf16* __restrict__ kh,
            const bf16* __restrict__ vt, const unsigned long long* __restrict__ mbits,
            float* __restrict__ wout, float* __restrict__ ao) {
  __shared__ bf16 lW[4][32 * 40];     // per-wave P tile: [32 q][32 sk + 8 pad]

  const int tid = threadIdx.x, lane = tid & 63, wave = tid >> 6;
  const int hb = blockIdx.y;                       // h*2 + b
  const int q0 = blockIdx.x * 128 + wave * 32;     // this wave's 32 q rows
  const bf16* Kb = kh + (size_t)hb * S * DH;
  const bf16* Vb = vt + (size_t)hb * DH * S;
  const bf16* Qb = qh + (size_t)hb * S * DH;
  const int lr = lane & 15, lg = lane >> 4;
  const float scale = 0.125f;                       // 1/sqrt(64)

  // Q fragments in registers: 2 m-frags x 2 k-chunks (Dh=64)
  bf16x8 qf[2][2];
  #pragma unroll
  for (int mf = 0; mf < 2; ++mf)
    #pragma unroll
    for (int kk = 0; kk < 2; ++kk)
      qf[mf][kk] = *(const bf16x8*)&Qb[(size_t)(q0 + mf * 16 + lr) * DH + kk * 32 + lg * 8];

  float mrow[2][4], lrow[2][4];
  #pragma unroll
  for (int mf = 0; mf < 2; ++mf)
    #pragma unroll
    for (int j = 0; j < 4; ++j) { mrow[mf][j] = -3.0e38f; lrow[mf][j] = 0.f; }

  // ---- pass 1: online (m, l) ----
  for (int t = 0; t < 32; ++t) {
    f32x4 sa[2][4];
    #pragma unroll
    for (int c = 0; c < 4; ++c) {
      const bf16* kr = &Kb[(size_t)(t * 64 + c * 16 + lr) * DH + lg * 8];
      bf16x8 k0v = *(const bf16x8*)kr;
      bf16x8 k1v = *(const bf16x8*)(kr + 32);
      #pragma unroll
      for (int mf = 0; mf < 2; ++mf) {
        f32x4 z = {0.f, 0.f, 0.f, 0.f};
        z = mfma16(qf[mf][0], k0v, z);
        sa[mf][c] = mfma16(qf[mf][1], k1v, z);
      }
    }
    #pragma unroll
    for (int mf = 0; mf < 2; ++mf) {
      #pragma unroll
      for (int j = 0; j < 4; ++j) {
        unsigned long long mw = mbits[(size_t)(q0 + mf * 16 + lg * 4 + j) * 32 + t];
        float sv[4];
        #pragma unroll
        for (int c = 0; c < 4; ++c) {
          int cb = c * 16 + lr;
          sv[c] = ((mw >> cb) & 1ull) ? sa[mf][c][j] * scale : -1e9f;
        }
        float tmax = fmaxf(fmaxf(sv[0], sv[1]), fmaxf(sv[2], sv[3]));
        float mo = mrow[mf][j];
        float mn = fmaxf(mo, tmax);
        lrow[mf][j] = lrow[mf][j] * __expf(mo - mn)
                    + __expf(sv[0] - mn) + __expf(sv[1] - mn)
                    + __expf(sv[2] - mn) + __expf(sv[3] - mn);
        mrow[mf][j] = mn;
      }
    }
  }
  // cross-lane combine over the 16 lanes sharing a row
  #pragma unroll
  for (int mf = 0; mf < 2; ++mf)
    #pragma unroll
    for (int j = 0; j < 4; ++j) {
      float m = mrow[mf][j], l = lrow[mf][j];
      #pragma unroll
      for (int off = 1; off < 16; off <<= 1) {
        float mo = __shfl_xor(m, off, 16);
        float lo = __shfl_xor(l, off, 16);
        float mn = fmaxf(m, mo);
        l = l * __expf(m - mn) + lo * __expf(mo - mn);
        m = mn;
      }
      mrow[mf][j] = m;
      lrow[mf][j] = 1.0f / l;   // 1/sum
    }

  // ---- pass 2: weights write + PV ----
  f32x4 oacc[2][4] = {};
  for (int t = 0; t < 32; ++t) {
    f32x4 sa[2][4];
    #pragma unroll
    for (int c = 0; c < 4; ++c) {
      const bf16* kr = &Kb[(size_t)(t * 64 + c * 16 + lr) * DH + lg * 8];
      bf16x8 k0v = *(const bf16x8*)kr;
      bf16x8 k1v = *(const bf16x8*)(kr + 32);
      #pragma unroll
      for (int mf = 0; mf < 2; ++mf) {
        f32x4 z = {0.f, 0.f, 0.f, 0.f};
        z = mfma16(qf[mf][0], k0v, z);
        sa[mf][c] = mfma16(qf[mf][1], k1v, z);
      }
    }
    #pragma unroll
    for (int u = 0; u < 2; ++u) {          // two 32-sk chunks
      #pragma unroll
      for (int mf = 0; mf < 2; ++mf) {
        #pragma unroll
        for (int cc = 0; cc < 2; ++cc) {
          int c = u * 2 + cc;
          int cb = c * 16 + lr;
          unsigned long long mw0 = mbits[(size_t)(q0 + mf * 16 + lg * 4 + 0) * 32 + t];
          unsigned long long mw1 = mbits[(size_t)(q0 + mf * 16 + lg * 4 + 1) * 32 + t];
          unsigned long long mw2 = mbits[(size_t)(q0 + mf * 16 + lg * 4 + 2) * 32 + t];
          unsigned long long mw3 = mbits[(size_t)(q0 + mf * 16 + lg * 4 + 3) * 32 + t];
          unsigned long long mw[4] = {mw0, mw1, mw2, mw3};
          #pragma unroll
          for (int j = 0; j < 4; ++j) {
            float sv = ((mw[j] >> cb) & 1ull) ? sa[mf][c][j] * scale : -1e9f;
            float w = __expf(sv - mrow[mf][j]) * lrow[mf][j];
            int row = mf * 16 + lg * 4 + j;
            wout[(size_t)(hb * S + q0 + row) * S + t * 64 + cb] = w;
            lW[wave][row * 40 + cc * 16 + lr] = __float2bfloat16(w);
          }
        }
      }
      // PV for this 32-sk chunk (per-wave LDS, same-wave deps, no barrier)
      #pragma unroll
      for (int mf = 0; mf < 2; ++mf) {
        bf16x8 pa = *(const bf16x8*)&lW[wave][(mf * 16 + lr) * 40 + lg * 8];
        #pragma unroll
        for (int nf = 0; nf < 4; ++nf) {
          bf16x8 vb = *(const bf16x8*)&Vb[(size_t)(nf * 16 + lr) * S + t * 64 + u * 32 + lg * 8];
          oacc[mf][nf] = mfma16(pa, vb, oacc[mf][nf]);
        }
      }
    }
  }

  // epilogue: attn output -> ws as f32 [m = s*2+b][d = h*64+dh]
  int h = hb >> 1, b = hb & 1;
  #pragma unroll
  for (int mf = 0; mf < 2; ++mf)
    #pragma unroll
    for (int nf = 0; nf < 4; ++nf)
      #pragma unroll
      for (int r = 0; r < 4; ++r) {
        int sq = q0 + mf * 16 + lg * 4 + r;
        int d  = h * 64 + nf * 16 + lr;
        ao[(size_t)(sq * 2 + b) * D + d] = oacc[mf][nf][r];
      }
}

// ---------------- host ----------------
extern "C" void kernel_launch(void* const* d_in, const int* in_sizes, int n_in,
                              void* d_out, int out_size, void* d_ws, size_t ws_size,
                              hipStream_t stream) {
  const float* q    = (const float*)d_in[0];
  const float* k    = (const float*)d_in[1];
  const float* v    = (const float*)d_in[2];
  const int*   mask = (const int*)d_in[3];
  const float* Wq   = (const float*)d_in[4];
  const float* bq   = (const float*)d_in[5];
  const float* Wk   = (const float*)d_in[6];
  const float* bk   = (const float*)d_in[7];
  const float* Wv   = (const float*)d_in[8];
  const float* bv   = (const float*)d_in[9];
  const float* Wo   = (const float*)d_in[10];
  const float* bo   = (const float*)d_in[11];

  char* ws = (char*)d_ws;
  bf16* qh = (bf16*)(ws);                              // 8 MB  [H,B,S,Dh]
  bf16* kh = (bf16*)(ws + ((size_t)8  << 20));         // 8 MB  [H,B,S,Dh]
  bf16* vt = (bf16*)(ws + ((size_t)16 << 20));         // 8 MB  [H,B,Dh,S]
  float* ao = (float*)(ws + ((size_t)24 << 20));       // 16 MB [M,D]
  unsigned long long* mbits =
      (unsigned long long*)(ws + ((size_t)40 << 20));  // 512 KB

  float* outp = (float*)d_out;
  float* wout = outp + (size_t)M * D;                  // weights at +4194304

  maskbits_k<<<dim3((S * S) / 256), 256, 0, stream>>>(mask, mbits);

  dim3 gq(M / 128, D / 128, 3);   // 32 x 8 x 3
  gemm_qkv<<<gq, 256, 0, stream>>>(q, k, v, Wq, Wk, Wv, bq, bk, bv, qh, kh, vt);

  dim3 ga(S / 128, H * B);        // 16 x 32
  attn_k<<<ga, 256, 0, stream>>>(qh, kh, vt, mbits, wout, ao);

  dim3 gg(M / 128, D / 128);      // 32 x 8
  gemm_out<<<gg, 256, 0, stream>>>(ao, Wo, bo, outp);
}